// Round 1
// 1021.990 us; speedup vs baseline: 1.2603x; 1.2603x over previous
//
#include <hip/hip_runtime.h>
#include <stdint.h>

// Monarch attention, B=4 H=16 N=8192 D=64, b=128, m=64, T=3.
// Split-bf16 MFMA (hi+lo, 3 mfma per product) ~= fp32 precision at matrix-core rate.
// v2: occupancy-focused rewrite.
//  r_kernel: A-fragments (qbar) direct global->reg; K row-subtiled + X2^T subtiled via
//            shfl 4x4 transpose (XOR-swizzled, bank-uniform reads); R kept wave-local in a
//            2.5KB/wave chunked scratch (R rows never cross waves). LDS 106.5KB -> 64KB.
//  l/out:    drop row-major Q copy; sQT staged via shfl transpose. LDS 55.5KB -> 37KB.

#define BH   64
#define NTOK 8192
#define DD   64
#define MM   64
#define BBS  128

typedef __attribute__((ext_vector_type(8))) short bf16x8;
typedef __attribute__((ext_vector_type(4))) float f32x4;

union U8 { bf16x8 v; uint32_t u[4]; };

__device__ __forceinline__ f32x4 MF(bf16x8 a, bf16x8 b, f32x4 c){
    return __builtin_amdgcn_mfma_f32_16x16x32_bf16(a, b, c, 0, 0, 0);
}
__device__ __forceinline__ f32x4 MF3(bf16x8 ah, bf16x8 al, bf16x8 bh_, bf16x8 bl_, f32x4 c){
    c = MF(ah, bh_, c);
    c = MF(ah, bl_, c);
    c = MF(al, bh_, c);
    return c;
}

__device__ __forceinline__ ushort bf16h(float x){
    union{float f; uint32_t u;} v; v.f = x;
    return (ushort)((v.u + 0x7fffu + ((v.u >> 16) & 1u)) >> 16);
}
__device__ __forceinline__ float bf16f(ushort h){
    union{float f; uint32_t u;} v; v.u = ((uint32_t)h) << 16; return v.f;
}
__device__ __forceinline__ void split2(float x, ushort& h, ushort& l){
    h = bf16h(x);
    l = bf16h(x - bf16f(h));
}
__device__ __forceinline__ uint32_t packsplit(float x){
    ushort h, l; split2(x, h, l);
    return ((uint32_t)h << 16) | (uint32_t)l;
}
__device__ __forceinline__ void st2(ushort* p, ushort a, ushort b){
    *(uint32_t*)p = (uint32_t)a | ((uint32_t)b << 16);
}
__device__ __forceinline__ void pack2(float a, float b, uint32_t& hw, uint32_t& lw){
    ushort ah_, al_, bh2, bl2;
    split2(a, ah_, al_); split2(b, bh2, bl2);
    hw = (uint32_t)ah_ | ((uint32_t)bh2 << 16);
    lw = (uint32_t)al_ | ((uint32_t)bl2 << 16);
}

__device__ __forceinline__ float red16_max(float v){
    v = fmaxf(v, __shfl_xor(v, 1));
    v = fmaxf(v, __shfl_xor(v, 2));
    v = fmaxf(v, __shfl_xor(v, 4));
    v = fmaxf(v, __shfl_xor(v, 8));
    return v;
}
__device__ __forceinline__ float red16_sum(float v){
    v += __shfl_xor(v, 1);
    v += __shfl_xor(v, 2);
    v += __shfl_xor(v, 4);
    v += __shfl_xor(v, 8);
    return v;
}

// 4x4 transpose among quad lanes {t, t^16, t^32, t^48}; qpos = (t>>4)&3.
// In: x_c = X[qpos][c].  Out: z_c = X[c][qpos].   (verified butterfly)
__device__ __forceinline__ void tr4x4(int qpos, float x0, float x1, float x2, float x3,
                                      float& z0, float& z1, float& z2, float& z3){
    float s1 = (qpos&1) ? x0 : x1; float g1 = __shfl_xor(s1, 16);
    float s2 = (qpos&1) ? x2 : x3; float g2 = __shfl_xor(s2, 16);
    float y0 = (qpos&1) ? g1 : x0;
    float y1 = (qpos&1) ? x1 : g1;
    float y2 = (qpos&1) ? g2 : x2;
    float y3 = (qpos&1) ? x3 : g2;
    float u1 = (qpos&2) ? y0 : y2; float h1 = __shfl_xor(u1, 32);
    float u2 = (qpos&2) ? y1 : y3; float h2 = __shfl_xor(u2, 32);
    z0 = (qpos&2) ? h1 : y0;
    z2 = (qpos&2) ? y2 : h1;
    z1 = (qpos&2) ? h2 : y1;
    z3 = (qpos&2) ? y3 : h2;
}

// ---- Kbar0[bh][k][d] = mean over l' of K ----
__global__ __launch_bounds__(256) void kbar0_kernel(const float* __restrict__ K,
                                                    float* __restrict__ kbar0){
    const int k = blockIdx.x, bh = blockIdx.y;
    const int t = threadIdx.x;
    const int d = t & 63, p = t >> 6;
    __shared__ float part[4][64];
    const float* base = K + ((size_t)bh*NTOK + (size_t)k*BBS)*DD + d;
    float s = 0.f;
    for(int lp = p*32; lp < p*32 + 32; ++lp) s += base[(size_t)lp*DD];
    part[p][d] = s;
    __syncthreads();
    if(t < 64){
        float tot = part[0][t] + part[1][t] + part[2][t] + part[3][t];
        kbar0[((size_t)bh*MM + k)*DD + t] = tot * (1.0f/128.0f);
    }
}

// ---- L-step (MFMA): per (bh,l). S=Q Kbar^T, softmax_k -> L, Qbar = L^T Q / (w+eps) ----
// 37KB LDS -> 4 blocks/CU. Q^T staged via shfl transpose; GEMM1 A rebuilt from sQT columns.
__global__ __launch_bounds__(256, 4) void l_kernel(const float* __restrict__ Q,
                                                   const void* __restrict__ kb_in,
                                                   int mode, uint32_t* __restrict__ qbar){
    const int l = blockIdx.x, bh = blockIdx.y;
    const int t = threadIdx.x;
    __shared__ __align__(16) ushort sQTh[64*72], sQTl[64*72];
    __shared__ __align__(16) ushort sKh [64*72], sKl [64*72];   // aliased by sLT
    __shared__ float wsum[64];
    ushort* sLTh = sKh; ushort* sLTl = sKl;

    if(t < 64) wsum[t] = 0.f;

    const int w4 = t >> 4;              // 0..15
    const int qpos = w4 & 3;
    const int dq = (t & 15) << 2;
    // stage Q transposed only (shfl 4x4 transpose -> paired dword writes)
    #pragma unroll
    for(int j=0;j<4;++j){
        int i  = j*16 + w4;
        int ib = j*16 + (w4 & ~3);
        float4 v = *(const float4*)(Q + ((size_t)bh*NTOK + (size_t)i*BBS + l)*DD + dq);
        float z0,z1,z2,z3;
        tr4x4(qpos, v.x, v.y, v.z, v.w, z0, z1, z2, z3);   // z_c = Q[ib+c][dq+qpos]
        ushort h0,l0,h1,l1,h2,l2,h3,l3;
        split2(z0,h0,l0); split2(z1,h1,l1); split2(z2,h2,l2); split2(z3,h3,l3);
        int rowd = dq + qpos;
        st2(&sQTh[rowd*72 + ib],   h0,h1); st2(&sQTh[rowd*72 + ib+2], h2,h3);
        st2(&sQTl[rowd*72 + ib],   l0,l1); st2(&sQTl[rowd*72 + ib+2], l2,l3);
    }
    // stage Kbar hi/lo (unchanged)
    if(mode){
        const uint32_t* kp = (const uint32_t*)kb_in + ((size_t)bh*BBS + l)*(size_t)(MM*DD);
        #pragma unroll
        for(int j=0;j<8;++j){
            int f = (j*256+t)*2, k = f>>6, d = f&63;
            uint2 u = *(const uint2*)(kp + (size_t)k*DD + d);
            *(uint32_t*)&sKh[k*72+d] = (u.x >> 16)      | (u.y & 0xffff0000u);
            *(uint32_t*)&sKl[k*72+d] = (u.x & 0xffffu)  | (u.y << 16);
        }
    } else {
        const float* kp = (const float*)kb_in + (size_t)bh*(size_t)(MM*DD);
        #pragma unroll
        for(int j=0;j<4;++j){
            int idx = j*256+t, k = idx>>4, d = (idx&15)<<2;
            float4 v = *(const float4*)(kp + (size_t)k*DD + d);
            ushort h0,l0,h1,l1,h2,l2,h3,l3;
            split2(v.x,h0,l0); split2(v.y,h1,l1); split2(v.z,h2,l2); split2(v.w,h3,l3);
            st2(&sKh[k*72+d],   h0,h1); st2(&sKh[k*72+d+2], h2,h3);
            st2(&sKl[k*72+d],   l0,l1); st2(&sKl[k*72+d+2], l2,l3);
        }
    }
    __syncthreads();

    const int lane = t & 63, wv = t >> 6;
    const int n = lane & 15, qd = lane >> 4;
    const int m0 = wv * 16;

    // GEMM1: S = Q Kbar^T  (64x64, K=64); A built from sQT columns (broadcast reads)
    f32x4 accS[4] = {};
    #pragma unroll
    for(int kb=0;kb<2;++kb){
        int co = kb*32 + qd*8;
        U8 ah, al;
        #pragma unroll
        for(int jj=0;jj<4;++jj){
            uint32_t a0 = sQTh[(co+2*jj  )*72 + m0+n];
            uint32_t a1 = sQTh[(co+2*jj+1)*72 + m0+n];
            ah.u[jj] = a0 | (a1<<16);
            uint32_t b0 = sQTl[(co+2*jj  )*72 + m0+n];
            uint32_t b1 = sQTl[(co+2*jj+1)*72 + m0+n];
            al.u[jj] = b0 | (b1<<16);
        }
        #pragma unroll
        for(int c=0;c<4;++c){
            bf16x8 bh_ = *(const bf16x8*)&sKh[(c*16+n)*72 + co];
            bf16x8 bl_ = *(const bf16x8*)&sKl[(c*16+n)*72 + co];
            accS[c] = MF3(ah.v, al.v, bh_, bl_, accS[c]);
        }
    }
    __syncthreads();   // done reading sK -> sLT may overwrite

    // softmax rows, write L^T hi/lo, col-sums
    float colp[4] = {0.f,0.f,0.f,0.f};
    #pragma unroll
    for(int r=0;r<4;++r){
        float vals[4]; float mx = -3.4e38f;
        #pragma unroll
        for(int c=0;c<4;++c){ vals[c] = accS[c][r]*0.125f; mx = fmaxf(mx, vals[c]); }
        mx = red16_max(mx);
        float s = 0.f;
        #pragma unroll
        for(int c=0;c<4;++c){ vals[c] = __expf(vals[c]-mx); s += vals[c]; }
        s = red16_sum(s);
        float inv = 1.0f/s;
        int irow = m0 + qd*4 + r;
        #pragma unroll
        for(int c=0;c<4;++c){
            float Lv = vals[c]*inv;
            colp[c] += Lv;
            ushort hh, ll; split2(Lv, hh, ll);
            sLTh[(c*16+n)*72 + irow] = hh;
            sLTl[(c*16+n)*72 + irow] = ll;
        }
    }
    #pragma unroll
    for(int c=0;c<4;++c){
        float v = colp[c];
        v += __shfl_xor(v,16); v += __shfl_xor(v,32);
        if(qd == 0) atomicAdd(&wsum[c*16+n], v);
    }
    __syncthreads();

    // GEMM2: Qbar[k][d] = sum_i L^T[k][i] Q[i][d]
    f32x4 accQ[4] = {};
    #pragma unroll
    for(int kb=0;kb<2;++kb){
        int co = kb*32 + qd*8;
        bf16x8 ah = *(const bf16x8*)&sLTh[(m0+n)*72 + co];
        bf16x8 al = *(const bf16x8*)&sLTl[(m0+n)*72 + co];
        #pragma unroll
        for(int dt2=0;dt2<4;++dt2){
            bf16x8 bh_ = *(const bf16x8*)&sQTh[(dt2*16+n)*72 + co];
            bf16x8 bl_ = *(const bf16x8*)&sQTl[(dt2*16+n)*72 + co];
            accQ[dt2] = MF3(ah, al, bh_, bl_, accQ[dt2]);
        }
    }
    uint32_t* qb = qbar + ((size_t)bh*BBS + l)*(size_t)(MM*DD);
    #pragma unroll
    for(int r=0;r<4;++r){
        int krow = m0 + qd*4 + r;
        float invw = 1.0f/(wsum[krow] + 1e-6f);
        #pragma unroll
        for(int dt2=0;dt2<4;++dt2){
            qb[(size_t)krow*DD + dt2*16 + n] = packsplit(accQ[dt2][r]*invw);
        }
    }
}

// ---- R-step (MFMA): per (bh,k), 512 thr. S=Qbar K^T (128x128), softmax_{l'} -> R,
//      Kbar = R @ K (to kbar) or Vbar = R @ V (to d_out tokens).
// 64KB LDS -> 2 blocks/CU. A (qbar) direct global->reg; X1=K row-subtiled;
// XT = (V?V:K)^T subtiled via shfl transpose; R chunked in wave-local scratch over dead X1.
__global__ __launch_bounds__(512, 4) void r_kernel(const uint32_t* __restrict__ qbar,
                                                   const float* __restrict__ K,
                                                   const float* __restrict__ V,
                                                   uint32_t* __restrict__ outp, int outTok){
    const int k = blockIdx.x, bh = blockIdx.y;
    const int t = threadIdx.x;
    __shared__ __align__(16) ushort sm[32768];     // 64 KiB total
    ushort* X1h = sm;            // K row-subtiled [128/4][64/16][4][16], hi
    ushort* X1l = sm + 8192;
    ushort* XTh = sm + 16384;    // X2^T subtiled [64/4][128/16][4][16], hi
    ushort* XTl = sm + 24576;

    const int lane = t & 63, wv = t >> 6;
    const int n = lane & 15, qd = lane >> 4;
    const int m0 = wv * 16;

    // A-fragment loads (qbar rows m0+n are wave-private) -- issue first
    const uint32_t* qrow = qbar + (size_t)bh*BBS*(size_t)(MM*DD) + (size_t)k*DD
                         + (size_t)(m0+n)*(size_t)(MM*DD);
    uint4 qa0 = *(const uint4*)(qrow + qd*8);
    uint4 qa1 = *(const uint4*)(qrow + qd*8 + 4);
    uint4 qa2 = *(const uint4*)(qrow + 32 + qd*8);
    uint4 qa3 = *(const uint4*)(qrow + 32 + qd*8 + 4);

    // stage X1 = K (row-subtiled, XOR-swizzled) and XT = (V?V:K)^T (subtiled, XOR-swizzled)
    const float* kp = K + ((size_t)bh*NTOK + (size_t)k*BBS)*DD;
    const float* vp = V ? (V + ((size_t)bh*NTOK + (size_t)k*BBS)*DD) : kp;
    const int w4 = t >> 4;               // 0..31
    const int qpos = w4 & 3;
    const int dq = (t & 15) << 2;
    #pragma unroll
    for(int j=0;j<4;++j){
        int lp = j*32 + w4;
        float4 v = *(const float4*)(kp + (size_t)lp*DD + dq);
        ushort h0,l0,h1,l1,h2,l2,h3,l3;
        split2(v.x,h0,l0); split2(v.y,h1,l1); split2(v.z,h2,l2); split2(v.w,h3,l3);
        int e = ((lp>>2)<<8) + (((dq>>4)&3)<<6) + ((lp&3)<<4) + ((dq&15) ^ (((dq>>4)&1)<<3));
        st2(&X1h[e], h0,h1); st2(&X1h[e+2], h2,h3);
        st2(&X1l[e], l0,l1); st2(&X1l[e+2], l2,l3);

        float4 tv = v;
        if(V) tv = *(const float4*)(vp + (size_t)lp*DD + dq);
        float z0,z1,z2,z3;
        tr4x4(qpos, tv.x, tv.y, tv.z, tv.w, z0, z1, z2, z3);  // z_c = X2[lb+c][dq+qpos]
        int dv = dq + qpos;                  // XT row (0..63)
        int lb = j*32 + (w4 & ~3);           // XT col base (0..124)
        ushort th0,tl0,th1,tl1,th2,tl2,th3,tl3;
        split2(z0,th0,tl0); split2(z1,th1,tl1); split2(z2,th2,tl2); split2(z3,th3,tl3);
        int eT = ((dv>>2)<<9) + ((lb>>4)<<6) + ((dv&3)<<4) + ((lb&15) ^ (((dv>>2)&1)<<3));
        st2(&XTh[eT], th0,th1); st2(&XTh[eT+2], th2,th3);
        st2(&XTl[eT], tl0,tl1); st2(&XTl[eT+2], tl2,tl3);
    }
    __syncthreads();

    // unpack A fragments (packed u32 -> hi/lo bf16x8)
    U8 ah0, al0, ah1, al1;
    ah0.u[0] = (qa0.x>>16) | (qa0.y & 0xffff0000u);
    al0.u[0] = (qa0.x & 0xffffu) | (qa0.y<<16);
    ah0.u[1] = (qa0.z>>16) | (qa0.w & 0xffff0000u);
    al0.u[1] = (qa0.z & 0xffffu) | (qa0.w<<16);
    ah0.u[2] = (qa1.x>>16) | (qa1.y & 0xffff0000u);
    al0.u[2] = (qa1.x & 0xffffu) | (qa1.y<<16);
    ah0.u[3] = (qa1.z>>16) | (qa1.w & 0xffff0000u);
    al0.u[3] = (qa1.z & 0xffffu) | (qa1.w<<16);
    ah1.u[0] = (qa2.x>>16) | (qa2.y & 0xffff0000u);
    al1.u[0] = (qa2.x & 0xffffu) | (qa2.y<<16);
    ah1.u[1] = (qa2.z>>16) | (qa2.w & 0xffff0000u);
    al1.u[1] = (qa2.z & 0xffffu) | (qa2.w<<16);
    ah1.u[2] = (qa3.x>>16) | (qa3.y & 0xffff0000u);
    al1.u[2] = (qa3.x & 0xffffu) | (qa3.y<<16);
    ah1.u[3] = (qa3.z>>16) | (qa3.w & 0xffff0000u);
    al1.u[3] = (qa3.z & 0xffffu) | (qa3.w<<16);

    // GEMM1: S = Qbar K^T  (128x128, K-dim 64); B reads are bank-uniform
    const int base1 = (n>>2)*256 + (n&3)*16 + ((qd>>1)<<6) + ((8*(qd&1)) ^ (8*((qd>>1)&1)));
    f32x4 accS[8] = {};
    #pragma unroll
    for(int c=0;c<8;++c){
        bf16x8 bh_ = *(const bf16x8*)&X1h[base1 + c*1024];
        bf16x8 bl_ = *(const bf16x8*)&X1l[base1 + c*1024];
        accS[c] = MF3(ah0.v, al0.v, bh_, bl_, accS[c]);
    }
    #pragma unroll
    for(int c=0;c<8;++c){
        bf16x8 bh_ = *(const bf16x8*)&X1h[base1 + c*1024 + 128];
        bf16x8 bl_ = *(const bf16x8*)&X1l[base1 + c*1024 + 128];
        accS[c] = MF3(ah1.v, al1.v, bh_, bl_, accS[c]);
    }

    // softmax rows over 128 cols; keep probabilities in accS registers
    #pragma unroll
    for(int r=0;r<4;++r){
        float vals[8]; float mx = -3.4e38f;
        #pragma unroll
        for(int c=0;c<8;++c){ vals[c] = accS[c][r]*0.125f; mx = fmaxf(mx, vals[c]); }
        mx = red16_max(mx);
        float s = 0.f;
        #pragma unroll
        for(int c=0;c<8;++c){ vals[c] = __expf(vals[c]-mx); s += vals[c]; }
        s = red16_sum(s);
        float inv = 1.0f/s;
        #pragma unroll
        for(int c=0;c<8;++c) accS[c][r] = vals[c]*inv;
    }
    __syncthreads();   // all waves done reading X1 -> scratch may alias it

    // GEMM2: Out[l][d] = sum_{l'} R[l][l'] X2[l'][d], chunked over 4 k-steps of 32.
    // R rows needed by this wave are exactly the rows it computed: wave-local scratch.
    ushort* SWh = sm + wv*1280;          // [16][40] hi (stride 40 -> conflict-free reads)
    ushort* SWl = SWh + 640;             // [16][40] lo
    const int sw_rd = n*40 + qd*8;
    const int baseT = (n>>2)*512 + ((qd>>1)<<6) + (n&3)*16 + ((8*(qd&1)) ^ (8*((n>>2)&1)));
    f32x4 accO[4] = {};
    #pragma unroll
    for(int kb=0;kb<4;++kb){
        #pragma unroll
        for(int r=0;r<4;++r){
            #pragma unroll
            for(int c2=0;c2<2;++c2){
                ushort hh, ll;
                split2(accS[2*kb+c2][r], hh, ll);
                SWh[(qd*4+r)*40 + c2*16 + n] = hh;
                SWl[(qd*4+r)*40 + c2*16 + n] = ll;
            }
        }
        asm volatile("s_waitcnt lgkmcnt(0)" ::: "memory");  // wave-local write->read
        __builtin_amdgcn_sched_barrier(0);
        bf16x8 ah2 = *(const bf16x8*)&SWh[sw_rd];
        bf16x8 al2 = *(const bf16x8*)&SWl[sw_rd];
        #pragma unroll
        for(int dt2=0;dt2<4;++dt2){
            bf16x8 bh_ = *(const bf16x8*)&XTh[baseT + dt2*2048 + kb*128];
            bf16x8 bl_ = *(const bf16x8*)&XTl[baseT + dt2*2048 + kb*128];
            accO[dt2] = MF3(ah2, al2, bh_, bl_, accO[dt2]);
        }
        asm volatile("" ::: "memory");   // keep next chunk's writes after this chunk's reads
    }
    #pragma unroll
    for(int r=0;r<4;++r){
        int lrow = m0 + qd*4 + r;
        #pragma unroll
        for(int dt2=0;dt2<4;++dt2){
            uint32_t pw = packsplit(accO[dt2][r]);
            size_t off = outTok
                ? ((size_t)bh*NTOK + (size_t)k*BBS + lrow)*DD + dt2*16 + n
                : (((size_t)bh*BBS + lrow)*(size_t)MM + k)*DD + dt2*16 + n;
            outp[off] = pw;
        }
    }
}

// ---- Out (MFMA): per (bh,l). Recompute L3 from (Q,Kbar2); out = L3 @ Vbar ----
// 36KB LDS -> 4 blocks/CU. Q A-fragments direct from global (wave-private rows).
__global__ __launch_bounds__(256, 4) void out_kernel(const float* __restrict__ Q,
                                                     const uint32_t* __restrict__ kbar,
                                                     float* __restrict__ out){
    const int l = blockIdx.x, bh = blockIdx.y;
    const int t = threadIdx.x;
    __shared__ __align__(16) ushort sKh [64*72], sKl [64*72];   // aliased by sL
    __shared__ __align__(16) ushort sVTh[64*72], sVTl[64*72];
    ushort* sLh = sKh; ushort* sLl = sKl;

    const int lane = t & 63, wv = t >> 6;
    const int n = lane & 15, qd = lane >> 4;
    const int m0 = wv * 16;

    // A-fragments: Q rows m0+n direct from global (issued early)
    const float* qr = Q + ((size_t)bh*NTOK + (size_t)(m0+n)*BBS + l)*DD;
    float4 qv0 = *(const float4*)(qr + qd*8);
    float4 qv1 = *(const float4*)(qr + qd*8 + 4);
    float4 qv2 = *(const float4*)(qr + 32 + qd*8);
    float4 qv3 = *(const float4*)(qr + 32 + qd*8 + 4);

    // stage Kbar (packed)
    const uint32_t* kp = kbar + ((size_t)bh*BBS + l)*(size_t)(MM*DD);
    #pragma unroll
    for(int j=0;j<8;++j){
        int f = (j*256+t)*2, k = f>>6, d = f&63;
        uint2 u = *(const uint2*)(kp + (size_t)k*DD + d);
        *(uint32_t*)&sKh[k*72+d] = (u.x >> 16)     | (u.y & 0xffff0000u);
        *(uint32_t*)&sKl[k*72+d] = (u.x & 0xffffu) | (u.y << 16);
    }
    // stage Vbar (packed in d_out at tokens kk*b + l), transposed
    const uint32_t* vb = (const uint32_t*)out;
    #pragma unroll
    for(int j=0;j<16;++j){
        int idx = j*256+t, kk = idx>>6, d = idx&63;
        uint32_t u = vb[((size_t)bh*NTOK + (size_t)kk*BBS + l)*DD + d];
        sVTh[d*72+kk] = (ushort)(u >> 16);
        sVTl[d*72+kk] = (ushort)(u & 0xffffu);
    }
    __syncthreads();

    // unpack A fragments
    U8 ah0, al0, ah1, al1;
    pack2(qv0.x, qv0.y, ah0.u[0], al0.u[0]);
    pack2(qv0.z, qv0.w, ah0.u[1], al0.u[1]);
    pack2(qv1.x, qv1.y, ah0.u[2], al0.u[2]);
    pack2(qv1.z, qv1.w, ah0.u[3], al0.u[3]);
    pack2(qv2.x, qv2.y, ah1.u[0], al1.u[0]);
    pack2(qv2.z, qv2.w, ah1.u[1], al1.u[1]);
    pack2(qv3.x, qv3.y, ah1.u[2], al1.u[2]);
    pack2(qv3.z, qv3.w, ah1.u[3], al1.u[3]);

    // GEMM1: S = Q Kbar^T
    f32x4 accS[4] = {};
    #pragma unroll
    for(int kb=0;kb<2;++kb){
        int co = kb*32 + qd*8;
        const bf16x8 ah = kb ? ah1.v : ah0.v;
        const bf16x8 al = kb ? al1.v : al0.v;
        #pragma unroll
        for(int c=0;c<4;++c){
            bf16x8 bh_ = *(const bf16x8*)&sKh[(c*16+n)*72 + co];
            bf16x8 bl_ = *(const bf16x8*)&sKl[(c*16+n)*72 + co];
            accS[c] = MF3(ah, al, bh_, bl_, accS[c]);
        }
    }
    __syncthreads();   // done reading sK -> sL may overwrite

    // softmax -> L row-major hi/lo (wave-local rows)
    #pragma unroll
    for(int r=0;r<4;++r){
        float vals[4]; float mx = -3.4e38f;
        #pragma unroll
        for(int c=0;c<4;++c){ vals[c] = accS[c][r]*0.125f; mx = fmaxf(mx, vals[c]); }
        mx = red16_max(mx);
        float s = 0.f;
        #pragma unroll
        for(int c=0;c<4;++c){ vals[c] = __expf(vals[c]-mx); s += vals[c]; }
        s = red16_sum(s);
        float inv = 1.0f/s;
        int irow = m0 + qd*4 + r;
        #pragma unroll
        for(int c=0;c<4;++c){
            ushort hh, ll; split2(vals[c]*inv, hh, ll);
            sLh[irow*72 + c*16+n] = hh;
            sLl[irow*72 + c*16+n] = ll;
        }
    }
    __syncthreads();

    // GEMM2: O[i][d] = sum_k L[i][k] Vbar[k][d]
    f32x4 accO[4] = {};
    #pragma unroll
    for(int kb=0;kb<2;++kb){
        int co = kb*32 + qd*8;
        bf16x8 ah = *(const bf16x8*)&sLh[(m0+n)*72 + co];
        bf16x8 al = *(const bf16x8*)&sLl[(m0+n)*72 + co];
        #pragma unroll
        for(int dt2=0;dt2<4;++dt2){
            bf16x8 bh_ = *(const bf16x8*)&sVTh[(dt2*16+n)*72 + co];
            bf16x8 bl_ = *(const bf16x8*)&sVTl[(dt2*16+n)*72 + co];
            accO[dt2] = MF3(ah, al, bh_, bl_, accO[dt2]);
        }
    }
    #pragma unroll
    for(int r=0;r<4;++r){
        int irow = m0 + qd*4 + r;
        #pragma unroll
        for(int dt2=0;dt2<4;++dt2){
            out[((size_t)bh*NTOK + (size_t)irow*BBS + l)*DD + dt2*16 + n] = accO[dt2][r];
        }
    }
}

extern "C" void kernel_launch(void* const* d_in, const int* in_sizes, int n_in,
                              void* d_out, int out_size, void* d_ws, size_t ws_size,
                              hipStream_t stream){
    const float* Q = (const float*)d_in[0];
    const float* K = (const float*)d_in[1];
    const float* V = (const float*)d_in[2];
    float* out = (float*)d_out;
    const size_t big = (size_t)BH * BBS * MM * DD;     // 33,554,432
    uint32_t* qbar  = (uint32_t*)d_ws;
    uint32_t* kbar  = qbar + big;
    float*    kbar0 = (float*)(kbar + big);            // ~257 MiB total

    kbar0_kernel<<<dim3(MM, BH), 256, 0, stream>>>(K, kbar0);
    // step 0
    l_kernel<<<dim3(BBS, BH), 256, 0, stream>>>(Q, kbar0, 0, qbar);
    r_kernel<<<dim3(MM, BH), 512, 0, stream>>>(qbar, K, nullptr, kbar, 0);
    // step 1
    l_kernel<<<dim3(BBS, BH), 256, 0, stream>>>(Q, kbar, 1, qbar);
    r_kernel<<<dim3(MM, BH), 512, 0, stream>>>(qbar, K, nullptr, kbar, 0);
    // step 2
    l_kernel<<<dim3(BBS, BH), 256, 0, stream>>>(Q, kbar, 1, qbar);
    r_kernel<<<dim3(MM, BH), 512, 0, stream>>>(qbar, K, V, (uint32_t*)out, 1);  // Vbar
    // epilogue: recompute L3, out = L3 @ Vbar
    out_kernel<<<dim3(BBS, BH), 256, 0, stream>>>(Q, kbar, out);
}